// Round 5
// baseline (790.794 us; speedup 1.0000x reference)
//
#include <hip/hip_runtime.h>
#include <cstdint>
#include <cstddef>

typedef unsigned short u16;
using half4 = __attribute__((ext_vector_type(4))) _Float16;
using half8 = __attribute__((ext_vector_type(8))) _Float16;
using f32x4 = __attribute__((ext_vector_type(4))) float;
using f4    = __attribute__((ext_vector_type(4))) float;

#define B_    16
#define C_    256
#define H_    128
#define W_    128
#define C4_   64
#define COUT_ 256
#define HW_   (H_ * W_)

#define LDS_S1    264   // kernel1 slab [w][c]: 256 + 8 pad (octet-swizzled chunks)
#define QK_S      72    // kernel2 Q/K [h][d]: 64 + 8 pad
#define P_S       136   // kernel2 P   [h][g]: 128 + 8 pad
#define XP_S      140   // kernel2 epilogue transpose tile [c][h]

#define Q_ELEMS   ((size_t)B_ * W_ * H_ * C4_)      // 16,777,216
#define V_ELEMS   ((size_t)B_ * W_ * H_ * COUT_)    // 67,108,864
#define WS_NEED   (2 * Q_ELEMS * 2 + 2 * V_ELEMS * 2)  // 335,544,320 B

__device__ __forceinline__ u16 f16_rn(float f) {
  _Float16 h = (_Float16)f;   // RN
  return __builtin_bit_cast(u16, h);
}

// ---------------------------------------------------------------------------
// Kernel 1: Q/K/V 1x1-conv projections (fp16 operands, fp32 accum).
// Block = (src, b, h, w-half): 8192 small blocks, src interleaved on bit 0 so
// flow-readers and de_out-readers mix on every CU. LDS 33.8 KB, VGPR-capped
// via __launch_bounds__(256,3) -> 3 blocks/CU: staging of one block overlaps
// MFMA of the others (the R4 version was 1 block/CU, phase-serialized).
// Slab [256c][64w] fp32 -> fp16 LDS [w][c], octet swizzle:
//   (w,c) at w*LDS_S1 + ((c>>3)^((w>>2)&7))*8 + (c&7)
// ---------------------------------------------------------------------------
__device__ __forceinline__ const half8* afrag(const u16* __restrict__ ldsT,
                                              int w16, int ks, int lg) {
  int oct = (ks * 4 + lg) ^ ((w16 >> 2) & 7);
  return reinterpret_cast<const half8*>(&ldsT[w16 * LDS_S1 + oct * 8]);
}

__device__ __forceinline__ half8 wfrag(const float* __restrict__ Wm,
                                       int row, int ks, int lg) {
  const f4* wp = reinterpret_cast<const f4*>(Wm + (size_t)row * C_ + ks * 32 + lg * 8);
  f4 a = wp[0], b = wp[1];
  half8 r;
#pragma unroll
  for (int i = 0; i < 4; ++i) { r[i] = (_Float16)a[i]; r[4 + i] = (_Float16)b[i]; }
  return r;
}

// 64w x 64d projection (K or Q): wave wv owns d-tile wv. acc = 16 regs.
__device__ __forceinline__ void proj4(const u16* __restrict__ ldsT,
                                      const float* __restrict__ Wm,
                                      const float* __restrict__ bm,
                                      u16* __restrict__ dst,
                                      int b, int h, int w0, int wv, int col, int lg) {
  f32x4 zero = {0.f, 0.f, 0.f, 0.f};
  f32x4 acc[4];
#pragma unroll
  for (int i = 0; i < 4; ++i) acc[i] = zero;
#pragma unroll
  for (int ks = 0; ks < 8; ++ks) {
    half8 bfr = wfrag(Wm, wv * 16 + col, ks, lg);
#pragma unroll
    for (int wt = 0; wt < 4; ++wt) {
      const half8 afr = *afrag(ldsT, wt * 16 + col, ks, lg);
      acc[wt] = __builtin_amdgcn_mfma_f32_16x16x32_f16(afr, bfr, acc[wt], 0, 0, 0);
    }
  }
  const float bias = bm[wv * 16 + col];
#pragma unroll
  for (int wt = 0; wt < 4; ++wt)
#pragma unroll
    for (int r = 0; r < 4; ++r) {
      int w = w0 + wt * 16 + lg * 4 + r;
      dst[(((size_t)b * W_ + w) * H_ + h) * C4_ + wv * 16 + col] =
          f16_rn(acc[wt][r] + bias);
    }
}

__global__ void __launch_bounds__(256, 3) qkv_kernel(
    const float* __restrict__ flow, const float* __restrict__ de_out,
    const float* __restrict__ Wq, const float* __restrict__ bq,
    const float* __restrict__ Wk, const float* __restrict__ bk,
    const float* __restrict__ Wv, const float* __restrict__ bv,
    u16* __restrict__ Qws, u16* __restrict__ Kws, u16* __restrict__ Vws) {
  __shared__ __align__(16) u16 ldsT[64 * LDS_S1];
  const int t      = threadIdx.x;
  const int bid    = blockIdx.x;
  const int srcsel = bid & 1;          // 0: flow -> K,V   1: de_out -> Q
  const int rem    = bid >> 1;
  const int b      = rem >> 8;
  const int h      = (rem >> 1) & 127;
  const int w0     = (rem & 1) * 64;
  const int lane = t & 63;
  const int wv   = t >> 6;
  const int col  = lane & 15;
  const int lg   = lane >> 4;

  const float* src =
      (srcsel ? de_out : flow) + (size_t)b * C_ * HW_ + (size_t)h * W_ + w0;

  // ---- stage: 16 dwordx4 loads in flight, then convert+transpose to LDS ----
  f4 va[8], vb[8];
#pragma unroll
  for (int i = 0; i < 8; ++i) {
    const int u = i * 256 + t;
    const float* s0 = src + (size_t)(2 * (u >> 4)) * HW_ + (u & 15) * 4;
    va[i] = *reinterpret_cast<const f4*>(s0);
    vb[i] = *reinterpret_cast<const f4*>(s0 + HW_);
  }
#pragma unroll
  for (int i = 0; i < 8; ++i) {
    const int u = i * 256 + t;
    const int c = 2 * (u >> 4);
    const int q = u & 15;
#pragma unroll
    for (int j = 0; j < 4; ++j) {
      const int w   = q * 4 + j;
      const int oct = (c >> 3) ^ (q & 7);   // (w>>2)&7 == q&7 for j<4
      uint32_t pk = (uint32_t)f16_rn(va[i][j]) | ((uint32_t)f16_rn(vb[i][j]) << 16);
      *reinterpret_cast<uint32_t*>(&ldsT[w * LDS_S1 + oct * 8 + (c & 7)]) = pk;
    }
  }
  __syncthreads();

  if (srcsel == 0) {
    // ---- K ----
    proj4(ldsT, Wk, bk, Kws, b, h, w0, wv, col, lg);
    // ---- V: wave wv owns c-tiles [4wv,4wv+4); layout [b][w][g>>3][c][g&7] ----
    f32x4 zero = {0.f, 0.f, 0.f, 0.f};
    f32x4 acc[4][4];
#pragma unroll
    for (int j = 0; j < 4; ++j)
#pragma unroll
      for (int i = 0; i < 4; ++i) acc[j][i] = zero;
#pragma unroll
    for (int ks = 0; ks < 8; ++ks) {
      half8 bfr[4];
#pragma unroll
      for (int j = 0; j < 4; ++j)
        bfr[j] = wfrag(Wv, (wv * 4 + j) * 16 + col, ks, lg);
#pragma unroll
      for (int wt = 0; wt < 4; ++wt) {
        const half8 afr = *afrag(ldsT, wt * 16 + col, ks, lg);
#pragma unroll
        for (int j = 0; j < 4; ++j)
          acc[j][wt] =
              __builtin_amdgcn_mfma_f32_16x16x32_f16(afr, bfr[j], acc[j][wt], 0, 0, 0);
      }
    }
#pragma unroll
    for (int j = 0; j < 4; ++j) {
      const int co = (wv * 4 + j) * 16 + col;
      const float bias = bv[co];
#pragma unroll
      for (int wt = 0; wt < 4; ++wt)
#pragma unroll
        for (int r = 0; r < 4; ++r) {
          int w = w0 + wt * 16 + lg * 4 + r;
          Vws[(size_t)(b * W_ + w) * 32768 + ((h >> 3) * COUT_ + co) * 8 + (h & 7)] =
              f16_rn(acc[j][wt][r] + bias);
        }
    }
  } else {
    // ---- Q ----
    proj4(ldsT, Wq, bq, Qws, b, h, w0, wv, col, lg);
  }
}

// ---------------------------------------------------------------------------
// Kernel 2: per-(b,w)-column attention (unchanged from R4).
// ---------------------------------------------------------------------------
template <int EPI>
__global__ void __launch_bounds__(256) attn_kernel(
    const u16* __restrict__ Qws, const u16* __restrict__ Kws,
    const u16* __restrict__ Vws, u16* __restrict__ out_tmp,
    float* __restrict__ out) {
  __shared__ __align__(16) u16 ldsQK[2 * 128 * QK_S];  // P and epi-tile overlay

  const int t   = threadIdx.x;
  const int bid = blockIdx.x;
  const int sw  = (bid & 7) * 256 + (bid >> 3);  // bijective
  const int b   = sw >> 7;
  const int w   = sw & 127;
  const int lane = t & 63;
  const int wv   = t >> 6;
  const int col  = lane & 15;
  const int lg   = lane >> 4;

  const u16* qc    = Qws + ((size_t)b * W_ + w) * H_ * C4_;
  const u16* kc    = Kws + ((size_t)b * W_ + w) * H_ * C4_;
  const u16* vbase = Vws + (size_t)(b * W_ + w) * 32768;

  u16* ldsQ = ldsQK;
  u16* ldsK = ldsQK + 128 * QK_S;

#pragma unroll
  for (int i = 0; i < 4; ++i) {
    int item = i * 256 + t;
    int hh   = item >> 3;
    int d0   = (item & 7) * 8;
    *reinterpret_cast<half8*>(&ldsQ[hh * QK_S + d0]) =
        *reinterpret_cast<const half8*>(qc + item * 8);
    *reinterpret_cast<half8*>(&ldsK[hh * QK_S + d0]) =
        *reinterpret_cast<const half8*>(kc + item * 8);
  }
  __syncthreads();

  f32x4 zero = {0.f, 0.f, 0.f, 0.f};
  f32x4 e[2][8];
#pragma unroll
  for (int ht = 0; ht < 2; ++ht)
#pragma unroll
    for (int gt = 0; gt < 8; ++gt) e[ht][gt] = zero;

#pragma unroll
  for (int ks = 0; ks < 2; ++ks) {
    half8 aq[2];
#pragma unroll
    for (int ht = 0; ht < 2; ++ht)
      aq[ht] = *reinterpret_cast<const half8*>(
          &ldsQ[(wv * 32 + ht * 16 + col) * QK_S + ks * 32 + lg * 8]);
#pragma unroll
    for (int gt = 0; gt < 8; ++gt) {
      const half8 bk_ = *reinterpret_cast<const half8*>(
          &ldsK[(gt * 16 + col) * QK_S + ks * 32 + lg * 8]);
#pragma unroll
      for (int ht = 0; ht < 2; ++ht)
        e[ht][gt] = __builtin_amdgcn_mfma_f32_16x16x32_f16(aq[ht], bk_, e[ht][gt], 0, 0, 0);
    }
  }
  __syncthreads();  // Q/K dead -> region becomes P

  u16* ldsP = ldsQK + wv * 32 * P_S;  // wave-private slice

#pragma unroll
  for (int ht = 0; ht < 2; ++ht)
#pragma unroll
    for (int r = 0; r < 4; ++r) {
      float m = -1e30f;
#pragma unroll
      for (int gt = 0; gt < 8; ++gt) m = fmaxf(m, e[ht][gt][r]);
#pragma unroll
      for (int off = 1; off < 16; off <<= 1) m = fmaxf(m, __shfl_xor(m, off));
      float s = 0.f;
#pragma unroll
      for (int gt = 0; gt < 8; ++gt) {
        float p = __expf(e[ht][gt][r] - m);
        e[ht][gt][r] = p;
        s += p;
      }
#pragma unroll
      for (int off = 1; off < 16; off <<= 1) s += __shfl_xor(s, off);
      const float inv = 1.f / s;
      const int hh = ht * 16 + lg * 4 + r;
#pragma unroll
      for (int gt = 0; gt < 8; ++gt)
        ldsP[hh * P_S + gt * 16 + col] = f16_rn(e[ht][gt][r] * inv);
    }

  f32x4 o[2][16];
#pragma unroll
  for (int ht = 0; ht < 2; ++ht)
#pragma unroll
    for (int ct = 0; ct < 16; ++ct) o[ht][ct] = zero;

#pragma unroll
  for (int ks = 0; ks < 4; ++ks) {
    half8 ap[2];
#pragma unroll
    for (int ht = 0; ht < 2; ++ht)
      ap[ht] = *reinterpret_cast<const half8*>(
          &ldsP[(ht * 16 + col) * P_S + ks * 32 + lg * 8]);
#pragma unroll
    for (int ct = 0; ct < 16; ++ct) {
      const half8 bv_ = *reinterpret_cast<const half8*>(
          vbase + ((ks * 4 + lg) * COUT_ + ct * 16 + col) * 8);
#pragma unroll
      for (int ht = 0; ht < 2; ++ht)
        o[ht][ct] = __builtin_amdgcn_mfma_f32_16x16x32_f16(ap[ht], bv_, o[ht][ct], 0, 0, 0);
    }
  }

  if (EPI == 1) {
    u16* ldsX = ldsQK;  // reuse
    u16* dst_col = out_tmp + ((size_t)(b * W_ + w) << 15);
#pragma unroll
    for (int ctg = 0; ctg < 4; ++ctg) {
      __syncthreads();
#pragma unroll
      for (int j = 0; j < 4; ++j) {
        const int ct    = ctg * 4 + j;
        const int c_loc = j * 16 + col;
#pragma unroll
        for (int ht = 0; ht < 2; ++ht) {
          const int hbase = wv * 32 + ht * 16 + lg * 4;
          half4 pk;
#pragma unroll
          for (int r = 0; r < 4; ++r) pk[r] = (_Float16)o[ht][ct][r];
          *reinterpret_cast<half4*>(&ldsX[c_loc * XP_S + hbase]) = pk;
        }
      }
      __syncthreads();
      const int c_loc = t >> 2;
      const int h0    = (t & 3) * 32;
      u16* dp = dst_col + (ctg * 64 + c_loc) * 128 + h0;
#pragma unroll
      for (int k = 0; k < 4; ++k)
        *reinterpret_cast<half8*>(dp + k * 8) =
            *reinterpret_cast<const half8*>(&ldsX[c_loc * XP_S + h0 + k * 8]);
    }
  } else {
    float* outp = out + (size_t)b * COUT_ * HW_ + w;
#pragma unroll
    for (int ht = 0; ht < 2; ++ht)
#pragma unroll
      for (int ct = 0; ct < 16; ++ct)
#pragma unroll
        for (int r = 0; r < 4; ++r) {
          int hrow = wv * 32 + ht * 16 + lg * 4 + r;
          int c = ct * 16 + col;
          outp[((size_t)c * H_ + hrow) * W_] = o[ht][ct][r];
        }
  }
}

// ---------------------------------------------------------------------------
// Kernel 3: out_tmp[b][w][f] fp16 -> out[b][f][w] fp32 (unchanged from R4).
// ---------------------------------------------------------------------------
__global__ void __launch_bounds__(256) transpose_kernel(
    const u16* __restrict__ T, float* __restrict__ out) {
  __shared__ float lds[64 * 132];
  const int t   = threadIdx.x;
  const int bid = blockIdx.x;
  const int b   = bid >> 9;
  const int ft  = bid & 511;  // f-tile of 64

  {
    const int w  = t >> 1;
    const int fo = (t & 1) * 32;
    const u16* src = T + ((size_t)(b * W_ + w) << 15) + ft * 64 + fo;
#pragma unroll
    for (int k = 0; k < 4; ++k) {
      half8 v = *reinterpret_cast<const half8*>(src + k * 8);
#pragma unroll
      for (int e = 0; e < 8; ++e)
        lds[(fo + k * 8 + e) * 132 + w] = (float)v[e];
    }
  }
  __syncthreads();
  {
    const int f_loc = t >> 2;
    const int w0    = (t & 3) * 32;
    float* dst = out + (size_t)b * (COUT_ * HW_) + (size_t)(ft * 64 + f_loc) * 128 + w0;
#pragma unroll
    for (int k = 0; k < 8; ++k) {
      f4 v4;
#pragma unroll
      for (int e = 0; e < 4; ++e) v4[e] = lds[f_loc * 132 + w0 + k * 4 + e];
      *reinterpret_cast<f4*>(dst + k * 4) = v4;
    }
  }
}

extern "C" void kernel_launch(void* const* d_in, const int* in_sizes, int n_in,
                              void* d_out, int out_size, void* d_ws, size_t ws_size,
                              hipStream_t stream) {
  const float* flow   = (const float*)d_in[0];
  const float* de_out = (const float*)d_in[1];
  const float* Wq = (const float*)d_in[2];
  const float* bq = (const float*)d_in[3];
  const float* Wk = (const float*)d_in[4];
  const float* bk = (const float*)d_in[5];
  const float* Wv = (const float*)d_in[6];
  const float* bv = (const float*)d_in[7];
  float* out = (float*)d_out;

  u16* Qws = (u16*)d_ws;                 // [b][w][h][d]            fp16
  u16* Kws = Qws + Q_ELEMS;              // [b][w][h][d]            fp16
  u16* Vws = Kws + Q_ELEMS;              // [b][w][g>>3][c][g&7]    fp16
  u16* Tws = Vws + V_ELEMS;              // [b][w][c][h]            fp16

  qkv_kernel<<<2 * B_ * H_ * 2, 256, 0, stream>>>(flow, de_out, Wq, bq, Wk, bk,
                                                  Wv, bv, Qws, Kws, Vws);
  if (ws_size >= (size_t)WS_NEED) {
    attn_kernel<1><<<B_ * W_, 256, 0, stream>>>(Qws, Kws, Vws, Tws, out);
    transpose_kernel<<<B_ * 512, 256, 0, stream>>>(Tws, out);
  } else {
    attn_kernel<0><<<B_ * W_, 256, 0, stream>>>(Qws, Kws, Vws, Tws, out);
  }
}

// Round 6
// 552.331 us; speedup vs baseline: 1.4317x; 1.4317x over previous
//
#include <hip/hip_runtime.h>
#include <cstdint>
#include <cstddef>

typedef unsigned short u16;
using half4 = __attribute__((ext_vector_type(4))) _Float16;
using half8 = __attribute__((ext_vector_type(8))) _Float16;
using f32x4 = __attribute__((ext_vector_type(4))) float;
using f4    = __attribute__((ext_vector_type(4))) float;

#define B_    16
#define C_    256
#define H_    128
#define W_    128
#define C4_   64
#define COUT_ 256
#define HW_   (H_ * W_)

#define LDS_S1    264   // kernel1 slab [w][c]: 256 + 8 pad (octet-swizzled chunks)
#define QK_S      72    // kernel2 Q/K [h][d]: 64 + 8 pad
#define P_S       136   // kernel2 P   [h][g]: 128 + 8 pad
#define XP_S      140   // kernel2 epilogue transpose tile [c][h]

#define Q_ELEMS   ((size_t)B_ * W_ * H_ * C4_)      // 16,777,216
#define V_ELEMS   ((size_t)B_ * W_ * H_ * COUT_)    // 67,108,864
#define W16_ELEMS ((size_t)(C4_ * C_ + C4_ * C_ + COUT_ * C_))  // 98,304
// Q + K + V + W16 + out_tmp, all fp16
#define WS_NEED   ((2 * Q_ELEMS + 2 * V_ELEMS + W16_ELEMS) * 2)

__device__ __forceinline__ u16 f16_rn(float f) {
  _Float16 h = (_Float16)f;   // RN
  return __builtin_bit_cast(u16, h);
}

// ---------------------------------------------------------------------------
// Kernel 0: one-time fp32 -> fp16 weight conversion into ws.
// blocks 0..15 -> Wk, 16..31 -> Wq, 32..95 -> Wv. 4 elems/thread.
// ---------------------------------------------------------------------------
__global__ void __launch_bounds__(256) wconv_kernel(
    const float* __restrict__ Wk, const float* __restrict__ Wq,
    const float* __restrict__ Wv, u16* __restrict__ W16) {
  const int bid = blockIdx.x;
  const int t   = threadIdx.x;
  const float* src;
  u16* dst;
  int idx;
  if (bid < 16)      { src = Wk; dst = W16;                 idx = bid * 1024 + t * 4; }
  else if (bid < 32) { src = Wq; dst = W16 + C4_ * C_;      idx = (bid - 16) * 1024 + t * 4; }
  else               { src = Wv; dst = W16 + 2 * C4_ * C_;  idx = (bid - 32) * 1024 + t * 4; }
  f4 v = *reinterpret_cast<const f4*>(src + idx);
  half4 h;
#pragma unroll
  for (int i = 0; i < 4; ++i) h[i] = (_Float16)v[i];
  *reinterpret_cast<half4*>(dst + idx) = h;
}

// ---------------------------------------------------------------------------
// Kernel 1: Q/K/V 1x1-conv projections (fp16 operands, fp32 accum).
// Block = (srcsel, b, hgrp, w0, hlow) with bid = (g&7) + hlow*8 + (g>>3)*64:
//  * the 8 hlow-siblings of a group g share bid%8 (same XCD) and sit within
//    64 consecutive bids -> their 1/8-line V writes merge in that XCD's L2
//    (R5 lost this property: WRITE_SIZE 197 -> 625 MB; this restores it).
//  * XCD residue g&7 = (hgrp&3)*2 + w0: independent of srcsel -> balanced.
// Slab [256c][64w] fp32 -> fp16 LDS [w][c], octet swizzle:
//   (w,c) at w*LDS_S1 + ((c>>3)^((w>>2)&7))*8 + (c&7)
// Weights read as pre-converted fp16 fragments (single half8 load each).
// ---------------------------------------------------------------------------
__device__ __forceinline__ const half8* afrag(const u16* __restrict__ ldsT,
                                              int w16, int ks, int lg) {
  int oct = (ks * 4 + lg) ^ ((w16 >> 2) & 7);
  return reinterpret_cast<const half8*>(&ldsT[w16 * LDS_S1 + oct * 8]);
}

__device__ __forceinline__ const half8* whfrag(const u16* __restrict__ Wm16,
                                               int row, int ks, int lg) {
  return reinterpret_cast<const half8*>(Wm16 + (size_t)row * C_ + ks * 32 + lg * 8);
}

// 64w x 64d projection (K or Q): wave wv owns d-tile wv. acc = 16 regs.
__device__ __forceinline__ void proj4(const u16* __restrict__ ldsT,
                                      const u16* __restrict__ Wm16,
                                      const float* __restrict__ bm,
                                      u16* __restrict__ dst,
                                      int b, int h, int w0, int wv, int col, int lg) {
  f32x4 zero = {0.f, 0.f, 0.f, 0.f};
  f32x4 acc[4];
#pragma unroll
  for (int i = 0; i < 4; ++i) acc[i] = zero;
#pragma unroll
  for (int ks = 0; ks < 8; ++ks) {
    const half8 bfr = *whfrag(Wm16, wv * 16 + col, ks, lg);
#pragma unroll
    for (int wt = 0; wt < 4; ++wt) {
      const half8 afr = *afrag(ldsT, wt * 16 + col, ks, lg);
      acc[wt] = __builtin_amdgcn_mfma_f32_16x16x32_f16(afr, bfr, acc[wt], 0, 0, 0);
    }
  }
  const float bias = bm[wv * 16 + col];
#pragma unroll
  for (int wt = 0; wt < 4; ++wt)
#pragma unroll
    for (int r = 0; r < 4; ++r) {
      int w = w0 + wt * 16 + lg * 4 + r;
      dst[(((size_t)b * W_ + w) * H_ + h) * C4_ + wv * 16 + col] =
          f16_rn(acc[wt][r] + bias);
    }
}

__global__ void __launch_bounds__(256, 3) qkv_kernel(
    const float* __restrict__ flow, const float* __restrict__ de_out,
    const u16* __restrict__ W16,
    const float* __restrict__ bq, const float* __restrict__ bk,
    const float* __restrict__ bv,
    u16* __restrict__ Qws, u16* __restrict__ Kws, u16* __restrict__ Vws) {
  __shared__ __align__(16) u16 ldsT[64 * LDS_S1];
  const int t    = threadIdx.x;
  const int bid  = blockIdx.x;
  // sibling-colocating decomposition
  const int g      = (bid & 7) | ((bid >> 6) << 3);  // [0,1024)
  const int hlow   = (bid >> 3) & 7;
  const int w0     = (g & 1) * 64;
  const int hgrp   = (g >> 1) & 15;
  const int b      = (g >> 5) & 15;
  const int srcsel = g >> 9;
  const int h      = hgrp * 8 + hlow;
  const int lane = t & 63;
  const int wv   = t >> 6;
  const int col  = lane & 15;
  const int lg   = lane >> 4;

  const u16* Wk16 = W16;
  const u16* Wq16 = W16 + C4_ * C_;
  const u16* Wv16 = W16 + 2 * C4_ * C_;

  const float* src =
      (srcsel ? de_out : flow) + (size_t)b * C_ * HW_ + (size_t)h * W_ + w0;

  // ---- stage: 16 dwordx4 loads in flight, then convert+transpose to LDS ----
  f4 va[8], vb[8];
#pragma unroll
  for (int i = 0; i < 8; ++i) {
    const int u = i * 256 + t;
    const float* s0 = src + (size_t)(2 * (u >> 4)) * HW_ + (u & 15) * 4;
    va[i] = *reinterpret_cast<const f4*>(s0);
    vb[i] = *reinterpret_cast<const f4*>(s0 + HW_);
  }
#pragma unroll
  for (int i = 0; i < 8; ++i) {
    const int u = i * 256 + t;
    const int c = 2 * (u >> 4);
    const int q = u & 15;
#pragma unroll
    for (int j = 0; j < 4; ++j) {
      const int w   = q * 4 + j;
      const int oct = (c >> 3) ^ (q & 7);   // (w>>2)&7 == q&7 for j<4
      uint32_t pk = (uint32_t)f16_rn(va[i][j]) | ((uint32_t)f16_rn(vb[i][j]) << 16);
      *reinterpret_cast<uint32_t*>(&ldsT[w * LDS_S1 + oct * 8 + (c & 7)]) = pk;
    }
  }
  __syncthreads();

  if (srcsel == 0) {
    // ---- K ----
    proj4(ldsT, Wk16, bk, Kws, b, h, w0, wv, col, lg);
    // ---- V: wave wv owns c-tiles [4wv,4wv+4); layout [b][w][g>>3][c][g&7] ----
    f32x4 zero = {0.f, 0.f, 0.f, 0.f};
    f32x4 acc[4][4];
#pragma unroll
    for (int j = 0; j < 4; ++j)
#pragma unroll
      for (int i = 0; i < 4; ++i) acc[j][i] = zero;
#pragma unroll
    for (int ks = 0; ks < 8; ++ks) {
      half8 bfr[4];
#pragma unroll
      for (int j = 0; j < 4; ++j)
        bfr[j] = *whfrag(Wv16, (wv * 4 + j) * 16 + col, ks, lg);
#pragma unroll
      for (int wt = 0; wt < 4; ++wt) {
        const half8 afr = *afrag(ldsT, wt * 16 + col, ks, lg);
#pragma unroll
        for (int j = 0; j < 4; ++j)
          acc[j][wt] =
              __builtin_amdgcn_mfma_f32_16x16x32_f16(afr, bfr[j], acc[j][wt], 0, 0, 0);
      }
    }
#pragma unroll
    for (int j = 0; j < 4; ++j) {
      const int co = (wv * 4 + j) * 16 + col;
      const float bias = bv[co];
#pragma unroll
      for (int wt = 0; wt < 4; ++wt)
#pragma unroll
        for (int r = 0; r < 4; ++r) {
          int w = w0 + wt * 16 + lg * 4 + r;
          Vws[(size_t)(b * W_ + w) * 32768 + ((h >> 3) * COUT_ + co) * 8 + (h & 7)] =
              f16_rn(acc[j][wt][r] + bias);
        }
    }
  } else {
    // ---- Q ----
    proj4(ldsT, Wq16, bq, Qws, b, h, w0, wv, col, lg);
  }
}

// ---------------------------------------------------------------------------
// Kernel 2: per-(b,w)-column attention (unchanged).
// ---------------------------------------------------------------------------
template <int EPI>
__global__ void __launch_bounds__(256) attn_kernel(
    const u16* __restrict__ Qws, const u16* __restrict__ Kws,
    const u16* __restrict__ Vws, u16* __restrict__ out_tmp,
    float* __restrict__ out) {
  __shared__ __align__(16) u16 ldsQK[2 * 128 * QK_S];  // P and epi-tile overlay

  const int t   = threadIdx.x;
  const int bid = blockIdx.x;
  const int sw  = (bid & 7) * 256 + (bid >> 3);  // bijective
  const int b   = sw >> 7;
  const int w   = sw & 127;
  const int lane = t & 63;
  const int wv   = t >> 6;
  const int col  = lane & 15;
  const int lg   = lane >> 4;

  const u16* qc    = Qws + ((size_t)b * W_ + w) * H_ * C4_;
  const u16* kc    = Kws + ((size_t)b * W_ + w) * H_ * C4_;
  const u16* vbase = Vws + (size_t)(b * W_ + w) * 32768;

  u16* ldsQ = ldsQK;
  u16* ldsK = ldsQK + 128 * QK_S;

#pragma unroll
  for (int i = 0; i < 4; ++i) {
    int item = i * 256 + t;
    int hh   = item >> 3;
    int d0   = (item & 7) * 8;
    *reinterpret_cast<half8*>(&ldsQ[hh * QK_S + d0]) =
        *reinterpret_cast<const half8*>(qc + item * 8);
    *reinterpret_cast<half8*>(&ldsK[hh * QK_S + d0]) =
        *reinterpret_cast<const half8*>(kc + item * 8);
  }
  __syncthreads();

  f32x4 zero = {0.f, 0.f, 0.f, 0.f};
  f32x4 e[2][8];
#pragma unroll
  for (int ht = 0; ht < 2; ++ht)
#pragma unroll
    for (int gt = 0; gt < 8; ++gt) e[ht][gt] = zero;

#pragma unroll
  for (int ks = 0; ks < 2; ++ks) {
    half8 aq[2];
#pragma unroll
    for (int ht = 0; ht < 2; ++ht)
      aq[ht] = *reinterpret_cast<const half8*>(
          &ldsQ[(wv * 32 + ht * 16 + col) * QK_S + ks * 32 + lg * 8]);
#pragma unroll
    for (int gt = 0; gt < 8; ++gt) {
      const half8 bk_ = *reinterpret_cast<const half8*>(
          &ldsK[(gt * 16 + col) * QK_S + ks * 32 + lg * 8]);
#pragma unroll
      for (int ht = 0; ht < 2; ++ht)
        e[ht][gt] = __builtin_amdgcn_mfma_f32_16x16x32_f16(aq[ht], bk_, e[ht][gt], 0, 0, 0);
    }
  }
  __syncthreads();  // Q/K dead -> region becomes P

  u16* ldsP = ldsQK + wv * 32 * P_S;  // wave-private slice

#pragma unroll
  for (int ht = 0; ht < 2; ++ht)
#pragma unroll
    for (int r = 0; r < 4; ++r) {
      float m = -1e30f;
#pragma unroll
      for (int gt = 0; gt < 8; ++gt) m = fmaxf(m, e[ht][gt][r]);
#pragma unroll
      for (int off = 1; off < 16; off <<= 1) m = fmaxf(m, __shfl_xor(m, off));
      float s = 0.f;
#pragma unroll
      for (int gt = 0; gt < 8; ++gt) {
        float p = __expf(e[ht][gt][r] - m);
        e[ht][gt][r] = p;
        s += p;
      }
#pragma unroll
      for (int off = 1; off < 16; off <<= 1) s += __shfl_xor(s, off);
      const float inv = 1.f / s;
      const int hh = ht * 16 + lg * 4 + r;
#pragma unroll
      for (int gt = 0; gt < 8; ++gt)
        ldsP[hh * P_S + gt * 16 + col] = f16_rn(e[ht][gt][r] * inv);
    }

  f32x4 o[2][16];
#pragma unroll
  for (int ht = 0; ht < 2; ++ht)
#pragma unroll
    for (int ct = 0; ct < 16; ++ct) o[ht][ct] = zero;

#pragma unroll
  for (int ks = 0; ks < 4; ++ks) {
    half8 ap[2];
#pragma unroll
    for (int ht = 0; ht < 2; ++ht)
      ap[ht] = *reinterpret_cast<const half8*>(
          &ldsP[(ht * 16 + col) * P_S + ks * 32 + lg * 8]);
#pragma unroll
    for (int ct = 0; ct < 16; ++ct) {
      const half8 bv_ = *reinterpret_cast<const half8*>(
          vbase + ((ks * 4 + lg) * COUT_ + ct * 16 + col) * 8);
#pragma unroll
      for (int ht = 0; ht < 2; ++ht)
        o[ht][ct] = __builtin_amdgcn_mfma_f32_16x16x32_f16(ap[ht], bv_, o[ht][ct], 0, 0, 0);
    }
  }

  if (EPI == 1) {
    u16* ldsX = ldsQK;  // reuse
    u16* dst_col = out_tmp + ((size_t)(b * W_ + w) << 15);
#pragma unroll
    for (int ctg = 0; ctg < 4; ++ctg) {
      __syncthreads();
#pragma unroll
      for (int j = 0; j < 4; ++j) {
        const int ct    = ctg * 4 + j;
        const int c_loc = j * 16 + col;
#pragma unroll
        for (int ht = 0; ht < 2; ++ht) {
          const int hbase = wv * 32 + ht * 16 + lg * 4;
          half4 pk;
#pragma unroll
          for (int r = 0; r < 4; ++r) pk[r] = (_Float16)o[ht][ct][r];
          *reinterpret_cast<half4*>(&ldsX[c_loc * XP_S + hbase]) = pk;
        }
      }
      __syncthreads();
      const int c_loc = t >> 2;
      const int h0    = (t & 3) * 32;
      u16* dp = dst_col + (ctg * 64 + c_loc) * 128 + h0;
#pragma unroll
      for (int k = 0; k < 4; ++k)
        *reinterpret_cast<half8*>(dp + k * 8) =
            *reinterpret_cast<const half8*>(&ldsX[c_loc * XP_S + h0 + k * 8]);
    }
  } else {
    float* outp = out + (size_t)b * COUT_ * HW_ + w;
#pragma unroll
    for (int ht = 0; ht < 2; ++ht)
#pragma unroll
      for (int ct = 0; ct < 16; ++ct)
#pragma unroll
        for (int r = 0; r < 4; ++r) {
          int hrow = wv * 32 + ht * 16 + lg * 4 + r;
          int c = ct * 16 + col;
          outp[((size_t)c * H_ + hrow) * W_] = o[ht][ct][r];
        }
  }
}

// ---------------------------------------------------------------------------
// Kernel 3: out_tmp[b][w][f] fp16 -> out[b][f][w] fp32 (unchanged).
// ---------------------------------------------------------------------------
__global__ void __launch_bounds__(256) transpose_kernel(
    const u16* __restrict__ T, float* __restrict__ out) {
  __shared__ float lds[64 * 132];
  const int t   = threadIdx.x;
  const int bid = blockIdx.x;
  const int b   = bid >> 9;
  const int ft  = bid & 511;  // f-tile of 64

  {
    const int w  = t >> 1;
    const int fo = (t & 1) * 32;
    const u16* src = T + ((size_t)(b * W_ + w) << 15) + ft * 64 + fo;
#pragma unroll
    for (int k = 0; k < 4; ++k) {
      half8 v = *reinterpret_cast<const half8*>(src + k * 8);
#pragma unroll
      for (int e = 0; e < 8; ++e)
        lds[(fo + k * 8 + e) * 132 + w] = (float)v[e];
    }
  }
  __syncthreads();
  {
    const int f_loc = t >> 2;
    const int w0    = (t & 3) * 32;
    float* dst = out + (size_t)b * (COUT_ * HW_) + (size_t)(ft * 64 + f_loc) * 128 + w0;
#pragma unroll
    for (int k = 0; k < 8; ++k) {
      f4 v4;
#pragma unroll
      for (int e = 0; e < 4; ++e) v4[e] = lds[f_loc * 132 + w0 + k * 4 + e];
      *reinterpret_cast<f4*>(dst + k * 4) = v4;
    }
  }
}

extern "C" void kernel_launch(void* const* d_in, const int* in_sizes, int n_in,
                              void* d_out, int out_size, void* d_ws, size_t ws_size,
                              hipStream_t stream) {
  const float* flow   = (const float*)d_in[0];
  const float* de_out = (const float*)d_in[1];
  const float* Wq = (const float*)d_in[2];
  const float* bq = (const float*)d_in[3];
  const float* Wk = (const float*)d_in[4];
  const float* bk = (const float*)d_in[5];
  const float* Wv = (const float*)d_in[6];
  const float* bv = (const float*)d_in[7];
  float* out = (float*)d_out;

  u16* Qws = (u16*)d_ws;                 // [b][w][h][d]            fp16
  u16* Kws = Qws + Q_ELEMS;              // [b][w][h][d]            fp16
  u16* Vws = Kws + Q_ELEMS;              // [b][w][g>>3][c][g&7]    fp16
  u16* W16 = Vws + V_ELEMS;              // [Wk16|Wq16|Wv16]        fp16
  u16* Tws = W16 + W16_ELEMS;            // [b][w][c][h]            fp16

  wconv_kernel<<<96, 256, 0, stream>>>(Wk, Wq, Wv, W16);
  qkv_kernel<<<2 * B_ * H_ * 2, 256, 0, stream>>>(flow, de_out, W16, bq, bk, bv,
                                                  Qws, Kws, Vws);
  if (ws_size >= (size_t)WS_NEED) {
    attn_kernel<1><<<B_ * W_, 256, 0, stream>>>(Qws, Kws, Vws, Tws, out);
    transpose_kernel<<<B_ * 512, 256, 0, stream>>>(Tws, out);
  } else {
    attn_kernel<0><<<B_ * W_, 256, 0, stream>>>(Qws, Kws, Vws, Tws, out);
  }
}

// Round 8
// 547.611 us; speedup vs baseline: 1.4441x; 1.0086x over previous
//
#include <hip/hip_runtime.h>
#include <cstdint>
#include <cstddef>

typedef unsigned short u16;
using half4 = __attribute__((ext_vector_type(4))) _Float16;
using half8 = __attribute__((ext_vector_type(8))) _Float16;
using f32x4 = __attribute__((ext_vector_type(4))) float;
using f4    = __attribute__((ext_vector_type(4))) float;

#define B_    16
#define C_    256
#define H_    128
#define W_    128
#define C4_   64
#define COUT_ 256
#define HW_   (H_ * W_)

#define LDS_S1    264   // kernel1 T [w][c]: 256 + 8 pad (octet-swizzled chunks)
#define QK_S      72    // kernel2 Q/K [h][d]: 64 + 8 pad
#define P_S       136   // kernel2 P   [h][g]: 128 + 8 pad
#define XP_S      140   // kernel2 epilogue transpose tile [c][h]
#define O_S       72    // kernel1 out tile [w][d]: 64 + 8 pad

#define Q_ELEMS   ((size_t)B_ * W_ * H_ * C4_)      // 16,777,216
#define V_ELEMS   ((size_t)B_ * W_ * H_ * COUT_)    // 67,108,864
#define W16_ELEMS ((size_t)(C4_ * C_ + C4_ * C_ + COUT_ * C_))  // 98,304
#define WS_NEED   ((2 * Q_ELEMS + 2 * V_ELEMS + W16_ELEMS) * 2)

__device__ __forceinline__ u16 f16_rn(float f) {
  _Float16 h = (_Float16)f;   // RN
  return __builtin_bit_cast(u16, h);
}

__device__ __forceinline__ void gload16(const void* g, void* l) {
  __builtin_amdgcn_global_load_lds(
      (const __attribute__((address_space(1))) void*)g,
      (__attribute__((address_space(3))) void*)l, 16, 0, 0);
}

// ---------------------------------------------------------------------------
// Kernel 0: one-time fp32 -> fp16 weight conversion into ws.
// ---------------------------------------------------------------------------
__global__ void __launch_bounds__(256) wconv_kernel(
    const float* __restrict__ Wk, const float* __restrict__ Wq,
    const float* __restrict__ Wv, u16* __restrict__ W16) {
  const int bid = blockIdx.x;
  const int t   = threadIdx.x;
  const float* src;
  u16* dst;
  int idx;
  if (bid < 16)      { src = Wk; dst = W16;                 idx = bid * 1024 + t * 4; }
  else if (bid < 32) { src = Wq; dst = W16 + C4_ * C_;      idx = (bid - 16) * 1024 + t * 4; }
  else               { src = Wv; dst = W16 + 2 * C4_ * C_;  idx = (bid - 32) * 1024 + t * 4; }
  f4 v = *reinterpret_cast<const f4*>(src + idx);
  half4 h;
#pragma unroll
  for (int i = 0; i < 4; ++i) h[i] = (_Float16)v[i];
  *reinterpret_cast<half4*>(dst + idx) = h;
}

// ---------------------------------------------------------------------------
// Kernel 1: Q/K/V 1x1-conv projections (fp16 operands, fp32 accum).
// Staging via async global_load_lds (width 16, zero VGPR): 4 quarters of
// [64c][64w] fp32 -> linear F (16 KB) -> convert pass builds octet-swizzled
// fp16 T[w][c].
// K/Q outputs go through LDS (dead F region) -> full-line half8 stores.
// R7 BUG FIXED here: the O->global store covered only 2048 of 4096 elements
// (one half8/thread); now 2 x 256 half8s cover the full 64x64 tile.
// V keeps the sibling-merged scatter (bid map unchanged from R6).
// ---------------------------------------------------------------------------
__device__ __forceinline__ const half8* afrag(const u16* __restrict__ T,
                                              int w16, int ks, int lg) {
  int oct = (ks * 4 + lg) ^ ((w16 >> 2) & 7);
  return reinterpret_cast<const half8*>(&T[w16 * LDS_S1 + oct * 8]);
}

__device__ __forceinline__ const half8* whfrag(const u16* __restrict__ Wm16,
                                               int row, int ks, int lg) {
  return reinterpret_cast<const half8*>(Wm16 + (size_t)row * C_ + ks * 32 + lg * 8);
}

__global__ void __launch_bounds__(256, 3) qkv_kernel(
    const float* __restrict__ flow, const float* __restrict__ de_out,
    const u16* __restrict__ W16,
    const float* __restrict__ bq, const float* __restrict__ bk,
    const float* __restrict__ bv,
    u16* __restrict__ Qws, u16* __restrict__ Kws, u16* __restrict__ Vws) {
  __shared__ __align__(16) unsigned char ldsraw[16384 + 64 * LDS_S1 * 2];
  float* F = reinterpret_cast<float*>(ldsraw);            // [64][64] fp32 quarter
  u16*   T = reinterpret_cast<u16*>(ldsraw + 16384);      // [64][264] fp16 swizzled
  u16*   O = reinterpret_cast<u16*>(ldsraw);              // [64][72] out tile (reuses F)

  const int t    = threadIdx.x;
  const int bid  = blockIdx.x;
  // sibling-colocating decomposition (keeps V-write L2 merging)
  const int g      = (bid & 7) | ((bid >> 6) << 3);  // [0,1024)
  const int hlow   = (bid >> 3) & 7;
  const int w0     = (g & 1) * 64;
  const int hgrp   = (g >> 1) & 15;
  const int b      = (g >> 5) & 15;
  const int srcsel = g >> 9;
  const int h      = hgrp * 8 + hlow;
  const int lane = t & 63;
  const int wv   = t >> 6;
  const int col  = lane & 15;
  const int lg   = lane >> 4;

  const u16* Wk16 = W16;
  const u16* Wq16 = W16 + C4_ * C_;
  const u16* Wv16 = W16 + 2 * C4_ * C_;

  const float* src =
      (srcsel ? de_out : flow) + (size_t)b * C_ * HW_ + (size_t)h * W_ + w0;

  // ---- stage + convert: 4 quarters of 64 c-rows ----
  for (int qtr = 0; qtr < 4; ++qtr) {
    const float* s = src + (size_t)(qtr * 64) * HW_;
    // async global->LDS: wave wv covers rows [wv*16, wv*16+16), 4 rows/instr
#pragma unroll
    for (int i = 0; i < 4; ++i) {
      const int rr0 = wv * 16 + i * 4;
      gload16(s + (size_t)(rr0 + (lane >> 4)) * HW_ + (lane & 15) * 4,
              F + rr0 * 64);
    }
    __syncthreads();  // compiler drains vmcnt before barrier
    // convert quarter: F[rr][w] fp32 -> T[w][c] fp16 (octet swizzle)
#pragma unroll
    for (int i = 0; i < 2; ++i) {
      const int flat = i * 256 + t;            // [0,512)
      const int wq = flat & 15;                // w-quad
      const int pp = flat >> 4;                // local c-pair [0,32)
      const f4 fa = *reinterpret_cast<const f4*>(&F[(2 * pp) * 64 + wq * 4]);
      const f4 fb = *reinterpret_cast<const f4*>(&F[(2 * pp + 1) * 64 + wq * 4]);
      const int c   = qtr * 64 + 2 * pp;
      const int oct = (c >> 3) ^ (wq & 7);     // (w>>2)&7 == wq
#pragma unroll
      for (int j = 0; j < 4; ++j) {
        const int w = wq * 4 + j;
        uint32_t pk = (uint32_t)f16_rn(fa[j]) | ((uint32_t)f16_rn(fb[j]) << 16);
        *reinterpret_cast<uint32_t*>(&T[w * LDS_S1 + oct * 8 + (c & 7)]) = pk;
      }
    }
    __syncthreads();  // T chunk done; F safe to overwrite next quarter
  }

  if (srcsel == 0) {
    // ---- K: wave wv owns d-tile wv ----
    f32x4 zero = {0.f, 0.f, 0.f, 0.f};
    {
      f32x4 acc[4];
#pragma unroll
      for (int i = 0; i < 4; ++i) acc[i] = zero;
#pragma unroll
      for (int ks = 0; ks < 8; ++ks) {
        const half8 bfr = *whfrag(Wk16, wv * 16 + col, ks, lg);
#pragma unroll
        for (int wt = 0; wt < 4; ++wt) {
          const half8 afr = *afrag(T, wt * 16 + col, ks, lg);
          acc[wt] = __builtin_amdgcn_mfma_f32_16x16x32_f16(afr, bfr, acc[wt], 0, 0, 0);
        }
      }
      const float bias = bk[wv * 16 + col];
#pragma unroll
      for (int wt = 0; wt < 4; ++wt)
#pragma unroll
        for (int r = 0; r < 4; ++r)
          O[(wt * 16 + lg * 4 + r) * O_S + wv * 16 + col] = f16_rn(acc[wt][r] + bias);
    }
    __syncthreads();
    {  // coalesced K store: 512 half8s = full 64x64 tile
#pragma unroll
      for (int i = 0; i < 2; ++i) {
        const int item = i * 256 + t;      // [0,512)
        const int wl = item >> 3;          // [0,64)
        const int d0 = (item & 7) * 8;     // 0..56
        *reinterpret_cast<half8*>(
            &Kws[(((size_t)b * W_ + w0 + wl) * H_ + h) * C4_ + d0]) =
            *reinterpret_cast<const half8*>(&O[wl * O_S + d0]);
      }
    }
    // ---- V: wave wv owns c-tiles [4wv,4wv+4); layout [b][w][g>>3][c][g&7] ----
    f32x4 acc[4][4];
#pragma unroll
    for (int j = 0; j < 4; ++j)
#pragma unroll
      for (int i = 0; i < 4; ++i) acc[j][i] = zero;
#pragma unroll
    for (int ks = 0; ks < 8; ++ks) {
      half8 bfr[4];
#pragma unroll
      for (int j = 0; j < 4; ++j)
        bfr[j] = *whfrag(Wv16, (wv * 4 + j) * 16 + col, ks, lg);
#pragma unroll
      for (int wt = 0; wt < 4; ++wt) {
        const half8 afr = *afrag(T, wt * 16 + col, ks, lg);
#pragma unroll
        for (int j = 0; j < 4; ++j)
          acc[j][wt] =
              __builtin_amdgcn_mfma_f32_16x16x32_f16(afr, bfr[j], acc[j][wt], 0, 0, 0);
      }
    }
#pragma unroll
    for (int j = 0; j < 4; ++j) {
      const int co = (wv * 4 + j) * 16 + col;
      const float bias = bv[co];
#pragma unroll
      for (int wt = 0; wt < 4; ++wt)
#pragma unroll
        for (int r = 0; r < 4; ++r) {
          int w = w0 + wt * 16 + lg * 4 + r;
          Vws[(size_t)(b * W_ + w) * 32768 + ((h >> 3) * COUT_ + co) * 8 + (h & 7)] =
              f16_rn(acc[j][wt][r] + bias);
        }
    }
  } else {
    // ---- Q ----
    f32x4 zero = {0.f, 0.f, 0.f, 0.f};
    f32x4 acc[4];
#pragma unroll
    for (int i = 0; i < 4; ++i) acc[i] = zero;
#pragma unroll
    for (int ks = 0; ks < 8; ++ks) {
      const half8 bfr = *whfrag(Wq16, wv * 16 + col, ks, lg);
#pragma unroll
      for (int wt = 0; wt < 4; ++wt) {
        const half8 afr = *afrag(T, wt * 16 + col, ks, lg);
        acc[wt] = __builtin_amdgcn_mfma_f32_16x16x32_f16(afr, bfr, acc[wt], 0, 0, 0);
      }
    }
    const float bias = bq[wv * 16 + col];
#pragma unroll
    for (int wt = 0; wt < 4; ++wt)
#pragma unroll
      for (int r = 0; r < 4; ++r)
        O[(wt * 16 + lg * 4 + r) * O_S + wv * 16 + col] = f16_rn(acc[wt][r] + bias);
    __syncthreads();
    {  // coalesced Q store: 512 half8s = full 64x64 tile
#pragma unroll
      for (int i = 0; i < 2; ++i) {
        const int item = i * 256 + t;
        const int wl = item >> 3;
        const int d0 = (item & 7) * 8;
        *reinterpret_cast<half8*>(
            &Qws[(((size_t)b * W_ + w0 + wl) * H_ + h) * C4_ + d0]) =
            *reinterpret_cast<const half8*>(&O[wl * O_S + d0]);
      }
    }
  }
}

// ---------------------------------------------------------------------------
// Kernel 2: per-(b,w)-column attention (unchanged).
// ---------------------------------------------------------------------------
template <int EPI>
__global__ void __launch_bounds__(256) attn_kernel(
    const u16* __restrict__ Qws, const u16* __restrict__ Kws,
    const u16* __restrict__ Vws, u16* __restrict__ out_tmp,
    float* __restrict__ out) {
  __shared__ __align__(16) u16 ldsQK[2 * 128 * QK_S];  // P and epi-tile overlay

  const int t   = threadIdx.x;
  const int bid = blockIdx.x;
  const int sw  = (bid & 7) * 256 + (bid >> 3);  // bijective
  const int b   = sw >> 7;
  const int w   = sw & 127;
  const int lane = t & 63;
  const int wv   = t >> 6;
  const int col  = lane & 15;
  const int lg   = lane >> 4;

  const u16* qc    = Qws + ((size_t)b * W_ + w) * H_ * C4_;
  const u16* kc    = Kws + ((size_t)b * W_ + w) * H_ * C4_;
  const u16* vbase = Vws + (size_t)(b * W_ + w) * 32768;

  u16* ldsQ = ldsQK;
  u16* ldsK = ldsQK + 128 * QK_S;

#pragma unroll
  for (int i = 0; i < 4; ++i) {
    int item = i * 256 + t;
    int hh   = item >> 3;
    int d0   = (item & 7) * 8;
    *reinterpret_cast<half8*>(&ldsQ[hh * QK_S + d0]) =
        *reinterpret_cast<const half8*>(qc + item * 8);
    *reinterpret_cast<half8*>(&ldsK[hh * QK_S + d0]) =
        *reinterpret_cast<const half8*>(kc + item * 8);
  }
  __syncthreads();

  f32x4 zero = {0.f, 0.f, 0.f, 0.f};
  f32x4 e[2][8];
#pragma unroll
  for (int ht = 0; ht < 2; ++ht)
#pragma unroll
    for (int gt = 0; gt < 8; ++gt) e[ht][gt] = zero;

#pragma unroll
  for (int ks = 0; ks < 2; ++ks) {
    half8 aq[2];
#pragma unroll
    for (int ht = 0; ht < 2; ++ht)
      aq[ht] = *reinterpret_cast<const half8*>(
          &ldsQ[(wv * 32 + ht * 16 + col) * QK_S + ks * 32 + lg * 8]);
#pragma unroll
    for (int gt = 0; gt < 8; ++gt) {
      const half8 bk_ = *reinterpret_cast<const half8*>(
          &ldsK[(gt * 16 + col) * QK_S + ks * 32 + lg * 8]);
#pragma unroll
      for (int ht = 0; ht < 2; ++ht)
        e[ht][gt] = __builtin_amdgcn_mfma_f32_16x16x32_f16(aq[ht], bk_, e[ht][gt], 0, 0, 0);
    }
  }
  __syncthreads();  // Q/K dead -> region becomes P

  u16* ldsP = ldsQK + wv * 32 * P_S;  // wave-private slice

#pragma unroll
  for (int ht = 0; ht < 2; ++ht)
#pragma unroll
    for (int r = 0; r < 4; ++r) {
      float m = -1e30f;
#pragma unroll
      for (int gt = 0; gt < 8; ++gt) m = fmaxf(m, e[ht][gt][r]);
#pragma unroll
      for (int off = 1; off < 16; off <<= 1) m = fmaxf(m, __shfl_xor(m, off));
      float s = 0.f;
#pragma unroll
      for (int gt = 0; gt < 8; ++gt) {
        float p = __expf(e[ht][gt][r] - m);
        e[ht][gt][r] = p;
        s += p;
      }
#pragma unroll
      for (int off = 1; off < 16; off <<= 1) s += __shfl_xor(s, off);
      const float inv = 1.f / s;
      const int hh = ht * 16 + lg * 4 + r;
#pragma unroll
      for (int gt = 0; gt < 8; ++gt)
        ldsP[hh * P_S + gt * 16 + col] = f16_rn(e[ht][gt][r] * inv);
    }

  f32x4 o[2][16];
#pragma unroll
  for (int ht = 0; ht < 2; ++ht)
#pragma unroll
    for (int ct = 0; ct < 16; ++ct) o[ht][ct] = zero;

#pragma unroll
  for (int ks = 0; ks < 4; ++ks) {
    half8 ap[2];
#pragma unroll
    for (int ht = 0; ht < 2; ++ht)
      ap[ht] = *reinterpret_cast<const half8*>(
          &ldsP[(ht * 16 + col) * P_S + ks * 32 + lg * 8]);
#pragma unroll
    for (int ct = 0; ct < 16; ++ct) {
      const half8 bv_ = *reinterpret_cast<const half8*>(
          vbase + ((ks * 4 + lg) * COUT_ + ct * 16 + col) * 8);
#pragma unroll
      for (int ht = 0; ht < 2; ++ht)
        o[ht][ct] = __builtin_amdgcn_mfma_f32_16x16x32_f16(ap[ht], bv_, o[ht][ct], 0, 0, 0);
    }
  }

  if (EPI == 1) {
    u16* ldsX = ldsQK;  // reuse
    u16* dst_col = out_tmp + ((size_t)(b * W_ + w) << 15);
#pragma unroll
    for (int ctg = 0; ctg < 4; ++ctg) {
      __syncthreads();
#pragma unroll
      for (int j = 0; j < 4; ++j) {
        const int ct    = ctg * 4 + j;
        const int c_loc = j * 16 + col;
#pragma unroll
        for (int ht = 0; ht < 2; ++ht) {
          const int hbase = wv * 32 + ht * 16 + lg * 4;
          half4 pk;
#pragma unroll
          for (int r = 0; r < 4; ++r) pk[r] = (_Float16)o[ht][ct][r];
          *reinterpret_cast<half4*>(&ldsX[c_loc * XP_S + hbase]) = pk;
        }
      }
      __syncthreads();
      const int c_loc = t >> 2;
      const int h0    = (t & 3) * 32;
      u16* dp = dst_col + (ctg * 64 + c_loc) * 128 + h0;
#pragma unroll
      for (int k = 0; k < 4; ++k)
        *reinterpret_cast<half8*>(dp + k * 8) =
            *reinterpret_cast<const half8*>(&ldsX[c_loc * XP_S + h0 + k * 8]);
    }
  } else {
    float* outp = out + (size_t)b * COUT_ * HW_ + w;
#pragma unroll
    for (int ht = 0; ht < 2; ++ht)
#pragma unroll
      for (int ct = 0; ct < 16; ++ct)
#pragma unroll
        for (int r = 0; r < 4; ++r) {
          int hrow = wv * 32 + ht * 16 + lg * 4 + r;
          int c = ct * 16 + col;
          outp[((size_t)c * H_ + hrow) * W_] = o[ht][ct][r];
        }
  }
}

// ---------------------------------------------------------------------------
// Kernel 3: out_tmp[b][w][f] fp16 -> out[b][f][w] fp32 (unchanged).
// ---------------------------------------------------------------------------
__global__ void __launch_bounds__(256) transpose_kernel(
    const u16* __restrict__ T, float* __restrict__ out) {
  __shared__ float lds[64 * 132];
  const int t   = threadIdx.x;
  const int bid = blockIdx.x;
  const int b   = bid >> 9;
  const int ft  = bid & 511;  // f-tile of 64

  {
    const int w  = t >> 1;
    const int fo = (t & 1) * 32;
    const u16* src = T + ((size_t)(b * W_ + w) << 15) + ft * 64 + fo;
#pragma unroll
    for (int k = 0; k < 4; ++k) {
      half8 v = *reinterpret_cast<const half8*>(src + k * 8);
#pragma unroll
      for (int e = 0; e < 8; ++e)
        lds[(fo + k * 8 + e) * 132 + w] = (float)v[e];
    }
  }
  __syncthreads();
  {
    const int f_loc = t >> 2;
    const int w0    = (t & 3) * 32;
    float* dst = out + (size_t)b * (COUT_ * HW_) + (size_t)(ft * 64 + f_loc) * 128 + w0;
#pragma unroll
    for (int k = 0; k < 8; ++k) {
      f4 v4;
#pragma unroll
      for (int e = 0; e < 4; ++e) v4[e] = lds[f_loc * 132 + w0 + k * 4 + e];
      *reinterpret_cast<f4*>(dst + k * 4) = v4;
    }
  }
}

extern "C" void kernel_launch(void* const* d_in, const int* in_sizes, int n_in,
                              void* d_out, int out_size, void* d_ws, size_t ws_size,
                              hipStream_t stream) {
  const float* flow   = (const float*)d_in[0];
  const float* de_out = (const float*)d_in[1];
  const float* Wq = (const float*)d_in[2];
  const float* bq = (const float*)d_in[3];
  const float* Wk = (const float*)d_in[4];
  const float* bk = (const float*)d_in[5];
  const float* Wv = (const float*)d_in[6];
  const float* bv = (const float*)d_in[7];
  float* out = (float*)d_out;

  u16* Qws = (u16*)d_ws;                 // [b][w][h][d]            fp16
  u16* Kws = Qws + Q_ELEMS;              // [b][w][h][d]            fp16
  u16* Vws = Kws + Q_ELEMS;              // [b][w][g>>3][c][g&7]    fp16
  u16* W16 = Vws + V_ELEMS;              // [Wk16|Wq16|Wv16]        fp16
  u16* Tws = W16 + W16_ELEMS;            // [b][w][c][h]            fp16

  wconv_kernel<<<96, 256, 0, stream>>>(Wk, Wq, Wv, W16);
  qkv_kernel<<<2 * B_ * H_ * 2, 256, 0, stream>>>(flow, de_out, W16, bq, bk, bv,
                                                  Qws, Kws, Vws);
  if (ws_size >= (size_t)WS_NEED) {
    attn_kernel<1><<<B_ * W_, 256, 0, stream>>>(Qws, Kws, Vws, Tws, out);
    transpose_kernel<<<B_ * 512, 256, 0, stream>>>(Tws, out);
  } else {
    attn_kernel<0><<<B_ * W_, 256, 0, stream>>>(Qws, Kws, Vws, Tws, out);
  }
}

// Round 9
// 539.119 us; speedup vs baseline: 1.4668x; 1.0158x over previous
//
#include <hip/hip_runtime.h>
#include <cstdint>
#include <cstddef>

typedef unsigned short u16;
using half4 = __attribute__((ext_vector_type(4))) _Float16;
using half8 = __attribute__((ext_vector_type(8))) _Float16;
using f32x4 = __attribute__((ext_vector_type(4))) float;
using f4    = __attribute__((ext_vector_type(4))) float;

#define B_    16
#define C_    256
#define H_    128
#define W_    128
#define C4_   64
#define COUT_ 256
#define HW_   (H_ * W_)

#define T_S       72    // kernel1 T [w][c-quarter]: 64 + 8 pad (octet-swizzled)
#define QK_S      72    // kernel2 Q/K [h][d]: 64 + 8 pad
#define P_S       136   // kernel2 P   [h][g]: 128 + 8 pad
#define XP_S      140   // kernel2 epilogue transpose tile [c][h]
#define O_S       72    // kernel1 out tile [w][d]: 64 + 8 pad

#define Q_ELEMS   ((size_t)B_ * W_ * H_ * C4_)      // 16,777,216
#define V_ELEMS   ((size_t)B_ * W_ * H_ * COUT_)    // 67,108,864
#define W16_ELEMS ((size_t)(C4_ * C_ + C4_ * C_ + COUT_ * C_))  // 98,304
#define WS_NEED   ((2 * Q_ELEMS + 2 * V_ELEMS + W16_ELEMS) * 2)

__device__ __forceinline__ u16 f16_rn(float f) {
  _Float16 h = (_Float16)f;   // RN
  return __builtin_bit_cast(u16, h);
}

__device__ __forceinline__ void gload16(const void* g, void* l) {
  __builtin_amdgcn_global_load_lds(
      (const __attribute__((address_space(1))) void*)g,
      (__attribute__((address_space(3))) void*)l, 16, 0, 0);
}

// ---------------------------------------------------------------------------
// Kernel 0: one-time fp32 -> fp16 weight conversion into ws.
// ---------------------------------------------------------------------------
__global__ void __launch_bounds__(256) wconv_kernel(
    const float* __restrict__ Wk, const float* __restrict__ Wq,
    const float* __restrict__ Wv, u16* __restrict__ W16) {
  const int bid = blockIdx.x;
  const int t   = threadIdx.x;
  const float* src;
  u16* dst;
  int idx;
  if (bid < 16)      { src = Wk; dst = W16;                 idx = bid * 1024 + t * 4; }
  else if (bid < 32) { src = Wq; dst = W16 + C4_ * C_;      idx = (bid - 16) * 1024 + t * 4; }
  else               { src = Wv; dst = W16 + 2 * C4_ * C_;  idx = (bid - 32) * 1024 + t * 4; }
  f4 v = *reinterpret_cast<const f4*>(src + idx);
  half4 h;
#pragma unroll
  for (int i = 0; i < 4; ++i) h[i] = (_Float16)v[i];
  *reinterpret_cast<half4*>(dst + idx) = h;
}

// ---------------------------------------------------------------------------
// Kernel 1: Q/K/V projections — counted-vmcnt pipelined staging (T3/T4).
// Per quarter q: {issue gloads for q+1 into F[(q+1)&1]} -> s_waitcnt vmcnt(4)
// (NOT 0 — the new quarter stays in flight across the barrier) -> convert
// F[q&1] -> T (octet-swizzled fp16, ONE c-quarter) -> barrier -> MFMA the two
// k-chunks of this quarter. R6/R8 drained vmcnt to 0 each quarter ->
// ~28% HBM duty cycle (1.78 of 6.3 TB/s measured); this keeps 4 gloads/wave
// outstanding continuously.
// Buffer safety: every writer/reader pair is separated by an all-arrive
// barrier (F parity: convert(q-1) finishes before barrier2(q-1), issue(q)
// after it; T: MFMA(q) before barrier1(q+1), convert(q+1) after it).
// ---------------------------------------------------------------------------
__device__ __forceinline__ const half8* afragq(const u16* __restrict__ T,
                                               int w16, int ksl, int lg) {
  int oct = (ksl * 4 + lg) ^ ((w16 >> 2) & 7);
  return reinterpret_cast<const half8*>(&T[w16 * T_S + oct * 8]);
}

__device__ __forceinline__ const half8* whfrag(const u16* __restrict__ Wm16,
                                               int row, int ks, int lg) {
  return reinterpret_cast<const half8*>(Wm16 + (size_t)row * C_ + ks * 32 + lg * 8);
}

__global__ void __launch_bounds__(256, 3) qkv_kernel(
    const float* __restrict__ flow, const float* __restrict__ de_out,
    const u16* __restrict__ W16,
    const float* __restrict__ bq, const float* __restrict__ bk,
    const float* __restrict__ bv,
    u16* __restrict__ Qws, u16* __restrict__ Kws, u16* __restrict__ Vws) {
  __shared__ __align__(16) unsigned char ldsraw[2 * 16384 + 64 * T_S * 2];
  float* Fbuf[2] = {reinterpret_cast<float*>(ldsraw),
                    reinterpret_cast<float*>(ldsraw + 16384)};
  u16* T = reinterpret_cast<u16*>(ldsraw + 32768);        // [64][72] fp16 quarter
  u16* O = reinterpret_cast<u16*>(ldsraw);                // [64][72] out tile (reuses F0)

  const int t    = threadIdx.x;
  const int bid  = blockIdx.x;
  // sibling-colocating decomposition (keeps V-write L2 merging)
  const int g      = (bid & 7) | ((bid >> 6) << 3);  // [0,1024)
  const int hlow   = (bid >> 3) & 7;
  const int w0     = (g & 1) * 64;
  const int hgrp   = (g >> 1) & 15;
  const int b      = (g >> 5) & 15;
  const int srcsel = g >> 9;
  const int h      = hgrp * 8 + hlow;
  const int lane = t & 63;
  const int wv   = t >> 6;
  const int col  = lane & 15;
  const int lg   = lane >> 4;

  const u16* Wk16 = W16;
  const u16* Wq16 = W16 + C4_ * C_;
  const u16* Wv16 = W16 + 2 * C4_ * C_;

  const float* src =
      (srcsel ? de_out : flow) + (size_t)b * C_ * HW_ + (size_t)h * W_ + w0;

  f32x4 zero = {0.f, 0.f, 0.f, 0.f};
  f32x4 acc0[4];                 // K (srcsel=0) or Q (srcsel=1)
  f32x4 accV[4][4];              // V (srcsel=0 only)
#pragma unroll
  for (int i = 0; i < 4; ++i) acc0[i] = zero;
#pragma unroll
  for (int j = 0; j < 4; ++j)
#pragma unroll
    for (int i = 0; i < 4; ++i) accV[j][i] = zero;

  // ---- prologue: issue quarter 0 ----
#pragma unroll
  for (int i = 0; i < 4; ++i) {
    const int rr0 = wv * 16 + i * 4;
    gload16(src + (size_t)(rr0 + (lane >> 4)) * HW_ + (lane & 15) * 4,
            Fbuf[0] + rr0 * 64);
  }

#pragma unroll
  for (int q = 0; q < 4; ++q) {
    float* Fc = Fbuf[q & 1];
    float* Fn = Fbuf[(q + 1) & 1];
    if (q < 3) {
      const float* s = src + (size_t)((q + 1) * 64) * HW_;
#pragma unroll
      for (int i = 0; i < 4; ++i) {
        const int rr0 = wv * 16 + i * 4;
        gload16(s + (size_t)(rr0 + (lane >> 4)) * HW_ + (lane & 15) * 4,
                Fn + rr0 * 64);
      }
      asm volatile("s_waitcnt vmcnt(4) lgkmcnt(0)\ns_barrier" ::: "memory");
    } else {
      asm volatile("s_waitcnt vmcnt(0) lgkmcnt(0)\ns_barrier" ::: "memory");
    }
    __builtin_amdgcn_sched_barrier(0);

    // ---- convert quarter: Fc[rr][w] fp32 -> T[w][c_loc] fp16 (octet swizzle)
#pragma unroll
    for (int i = 0; i < 2; ++i) {
      const int flat = i * 256 + t;            // [0,512)
      const int wq = flat & 15;                // w-quad
      const int pp = flat >> 4;                // local c-pair [0,32)
      const f4 fa = *reinterpret_cast<const f4*>(&Fc[(2 * pp) * 64 + wq * 4]);
      const f4 fb = *reinterpret_cast<const f4*>(&Fc[(2 * pp + 1) * 64 + wq * 4]);
      const int c_loc = 2 * pp;                // [0,64)
      const int oct   = (c_loc >> 3) ^ (wq & 7);
#pragma unroll
      for (int j = 0; j < 4; ++j) {
        const int w = wq * 4 + j;
        uint32_t pk = (uint32_t)f16_rn(fa[j]) | ((uint32_t)f16_rn(fb[j]) << 16);
        *reinterpret_cast<uint32_t*>(&T[w * T_S + oct * 8 + (c_loc & 7)]) = pk;
      }
    }
    asm volatile("s_waitcnt lgkmcnt(0)\ns_barrier" ::: "memory");
    __builtin_amdgcn_sched_barrier(0);

    // ---- MFMA this quarter's two k-chunks ----
#pragma unroll
    for (int ksl = 0; ksl < 2; ++ksl) {
      const int ks = 2 * q + ksl;
      if (srcsel == 0) {
        const half8 bK = *whfrag(Wk16, wv * 16 + col, ks, lg);
        half8 bV[4];
#pragma unroll
        for (int j = 0; j < 4; ++j)
          bV[j] = *whfrag(Wv16, (wv * 4 + j) * 16 + col, ks, lg);
#pragma unroll
        for (int wt = 0; wt < 4; ++wt) {
          const half8 afr = *afragq(T, wt * 16 + col, ksl, lg);
          acc0[wt] = __builtin_amdgcn_mfma_f32_16x16x32_f16(afr, bK, acc0[wt], 0, 0, 0);
#pragma unroll
          for (int j = 0; j < 4; ++j)
            accV[j][wt] =
                __builtin_amdgcn_mfma_f32_16x16x32_f16(afr, bV[j], accV[j][wt], 0, 0, 0);
        }
      } else {
        const half8 bQ = *whfrag(Wq16, wv * 16 + col, ks, lg);
#pragma unroll
        for (int wt = 0; wt < 4; ++wt) {
          const half8 afr = *afragq(T, wt * 16 + col, ksl, lg);
          acc0[wt] = __builtin_amdgcn_mfma_f32_16x16x32_f16(afr, bQ, acc0[wt], 0, 0, 0);
        }
      }
    }
    // MFMA(q) -> barrier1(q+1) -> convert(q+1): T overwrite is safe.
  }

  // ---- epilogue ----
  if (srcsel == 0) {
    {  // K via LDS O-tile (reuses F0; all gloads drained, T reads done)
      const float bias = bk[wv * 16 + col];
      __syncthreads();
#pragma unroll
      for (int wt = 0; wt < 4; ++wt)
#pragma unroll
        for (int r = 0; r < 4; ++r)
          O[(wt * 16 + lg * 4 + r) * O_S + wv * 16 + col] = f16_rn(acc0[wt][r] + bias);
      __syncthreads();
#pragma unroll
      for (int i = 0; i < 2; ++i) {
        const int item = i * 256 + t;      // [0,512)
        const int wl = item >> 3;          // [0,64)
        const int d0 = (item & 7) * 8;     // 0..56
        *reinterpret_cast<half8*>(
            &Kws[(((size_t)b * W_ + w0 + wl) * H_ + h) * C4_ + d0]) =
            *reinterpret_cast<const half8*>(&O[wl * O_S + d0]);
      }
    }
    // V: sibling-merged scatter, layout [b][w][g>>3][c][g&7]
#pragma unroll
    for (int j = 0; j < 4; ++j) {
      const int co = (wv * 4 + j) * 16 + col;
      const float bias = bv[co];
#pragma unroll
      for (int wt = 0; wt < 4; ++wt)
#pragma unroll
        for (int r = 0; r < 4; ++r) {
          int w = w0 + wt * 16 + lg * 4 + r;
          Vws[(size_t)(b * W_ + w) * 32768 + ((h >> 3) * COUT_ + co) * 8 + (h & 7)] =
              f16_rn(accV[j][wt][r] + bias);
        }
    }
  } else {
    const float bias = bq[wv * 16 + col];
    __syncthreads();
#pragma unroll
    for (int wt = 0; wt < 4; ++wt)
#pragma unroll
      for (int r = 0; r < 4; ++r)
        O[(wt * 16 + lg * 4 + r) * O_S + wv * 16 + col] = f16_rn(acc0[wt][r] + bias);
    __syncthreads();
#pragma unroll
    for (int i = 0; i < 2; ++i) {
      const int item = i * 256 + t;
      const int wl = item >> 3;
      const int d0 = (item & 7) * 8;
      *reinterpret_cast<half8*>(
          &Qws[(((size_t)b * W_ + w0 + wl) * H_ + h) * C4_ + d0]) =
          *reinterpret_cast<const half8*>(&O[wl * O_S + d0]);
    }
  }
}

// ---------------------------------------------------------------------------
// Kernel 2: per-(b,w)-column attention (unchanged).
// ---------------------------------------------------------------------------
template <int EPI>
__global__ void __launch_bounds__(256) attn_kernel(
    const u16* __restrict__ Qws, const u16* __restrict__ Kws,
    const u16* __restrict__ Vws, u16* __restrict__ out_tmp,
    float* __restrict__ out) {
  __shared__ __align__(16) u16 ldsQK[2 * 128 * QK_S];  // P and epi-tile overlay

  const int t   = threadIdx.x;
  const int bid = blockIdx.x;
  const int sw  = (bid & 7) * 256 + (bid >> 3);  // bijective
  const int b   = sw >> 7;
  const int w   = sw & 127;
  const int lane = t & 63;
  const int wv   = t >> 6;
  const int col  = lane & 15;
  const int lg   = lane >> 4;

  const u16* qc    = Qws + ((size_t)b * W_ + w) * H_ * C4_;
  const u16* kc    = Kws + ((size_t)b * W_ + w) * H_ * C4_;
  const u16* vbase = Vws + (size_t)(b * W_ + w) * 32768;

  u16* ldsQ = ldsQK;
  u16* ldsK = ldsQK + 128 * QK_S;

#pragma unroll
  for (int i = 0; i < 4; ++i) {
    int item = i * 256 + t;
    int hh   = item >> 3;
    int d0   = (item & 7) * 8;
    *reinterpret_cast<half8*>(&ldsQ[hh * QK_S + d0]) =
        *reinterpret_cast<const half8*>(qc + item * 8);
    *reinterpret_cast<half8*>(&ldsK[hh * QK_S + d0]) =
        *reinterpret_cast<const half8*>(kc + item * 8);
  }
  __syncthreads();

  f32x4 zero = {0.f, 0.f, 0.f, 0.f};
  f32x4 e[2][8];
#pragma unroll
  for (int ht = 0; ht < 2; ++ht)
#pragma unroll
    for (int gt = 0; gt < 8; ++gt) e[ht][gt] = zero;

#pragma unroll
  for (int ks = 0; ks < 2; ++ks) {
    half8 aq[2];
#pragma unroll
    for (int ht = 0; ht < 2; ++ht)
      aq[ht] = *reinterpret_cast<const half8*>(
          &ldsQ[(wv * 32 + ht * 16 + col) * QK_S + ks * 32 + lg * 8]);
#pragma unroll
    for (int gt = 0; gt < 8; ++gt) {
      const half8 bk_ = *reinterpret_cast<const half8*>(
          &ldsK[(gt * 16 + col) * QK_S + ks * 32 + lg * 8]);
#pragma unroll
      for (int ht = 0; ht < 2; ++ht)
        e[ht][gt] = __builtin_amdgcn_mfma_f32_16x16x32_f16(aq[ht], bk_, e[ht][gt], 0, 0, 0);
    }
  }
  __syncthreads();  // Q/K dead -> region becomes P

  u16* ldsP = ldsQK + wv * 32 * P_S;  // wave-private slice

#pragma unroll
  for (int ht = 0; ht < 2; ++ht)
#pragma unroll
    for (int r = 0; r < 4; ++r) {
      float m = -1e30f;
#pragma unroll
      for (int gt = 0; gt < 8; ++gt) m = fmaxf(m, e[ht][gt][r]);
#pragma unroll
      for (int off = 1; off < 16; off <<= 1) m = fmaxf(m, __shfl_xor(m, off));
      float s = 0.f;
#pragma unroll
      for (int gt = 0; gt < 8; ++gt) {
        float p = __expf(e[ht][gt][r] - m);
        e[ht][gt][r] = p;
        s += p;
      }
#pragma unroll
      for (int off = 1; off < 16; off <<= 1) s += __shfl_xor(s, off);
      const float inv = 1.f / s;
      const int hh = ht * 16 + lg * 4 + r;
#pragma unroll
      for (int gt = 0; gt < 8; ++gt)
        ldsP[hh * P_S + gt * 16 + col] = f16_rn(e[ht][gt][r] * inv);
    }

  f32x4 o[2][16];
#pragma unroll
  for (int ht = 0; ht < 2; ++ht)
#pragma unroll
    for (int ct = 0; ct < 16; ++ct) o[ht][ct] = zero;

#pragma unroll
  for (int ks = 0; ks < 4; ++ks) {
    half8 ap[2];
#pragma unroll
    for (int ht = 0; ht < 2; ++ht)
      ap[ht] = *reinterpret_cast<const half8*>(
          &ldsP[(ht * 16 + col) * P_S + ks * 32 + lg * 8]);
#pragma unroll
    for (int ct = 0; ct < 16; ++ct) {
      const half8 bv_ = *reinterpret_cast<const half8*>(
          vbase + ((ks * 4 + lg) * COUT_ + ct * 16 + col) * 8);
#pragma unroll
      for (int ht = 0; ht < 2; ++ht)
        o[ht][ct] = __builtin_amdgcn_mfma_f32_16x16x32_f16(ap[ht], bv_, o[ht][ct], 0, 0, 0);
    }
  }

  if (EPI == 1) {
    u16* ldsX = ldsQK;  // reuse
    u16* dst_col = out_tmp + ((size_t)(b * W_ + w) << 15);
#pragma unroll
    for (int ctg = 0; ctg < 4; ++ctg) {
      __syncthreads();
#pragma unroll
      for (int j = 0; j < 4; ++j) {
        const int ct    = ctg * 4 + j;
        const int c_loc = j * 16 + col;
#pragma unroll
        for (int ht = 0; ht < 2; ++ht) {
          const int hbase = wv * 32 + ht * 16 + lg * 4;
          half4 pk;
#pragma unroll
          for (int r = 0; r < 4; ++r) pk[r] = (_Float16)o[ht][ct][r];
          *reinterpret_cast<half4*>(&ldsX[c_loc * XP_S + hbase]) = pk;
        }
      }
      __syncthreads();
      const int c_loc = t >> 2;
      const int h0    = (t & 3) * 32;
      u16* dp = dst_col + (ctg * 64 + c_loc) * 128 + h0;
#pragma unroll
      for (int k = 0; k < 4; ++k)
        *reinterpret_cast<half8*>(dp + k * 8) =
            *reinterpret_cast<const half8*>(&ldsX[c_loc * XP_S + h0 + k * 8]);
    }
  } else {
    float* outp = out + (size_t)b * COUT_ * HW_ + w;
#pragma unroll
    for (int ht = 0; ht < 2; ++ht)
#pragma unroll
      for (int ct = 0; ct < 16; ++ct)
#pragma unroll
        for (int r = 0; r < 4; ++r) {
          int hrow = wv * 32 + ht * 16 + lg * 4 + r;
          int c = ct * 16 + col;
          outp[((size_t)c * H_ + hrow) * W_] = o[ht][ct][r];
        }
  }
}

// ---------------------------------------------------------------------------
// Kernel 3: out_tmp[b][w][f] fp16 -> out[b][f][w] fp32 (unchanged).
// ---------------------------------------------------------------------------
__global__ void __launch_bounds__(256) transpose_kernel(
    const u16* __restrict__ T, float* __restrict__ out) {
  __shared__ float lds[64 * 132];
  const int t   = threadIdx.x;
  const int bid = blockIdx.x;
  const int b   = bid >> 9;
  const int ft  = bid & 511;  // f-tile of 64

  {
    const int w  = t >> 1;
    const int fo = (t & 1) * 32;
    const u16* src = T + ((size_t)(b * W_ + w) << 15) + ft * 64 + fo;
#pragma unroll
    for (int k = 0; k < 4; ++k) {
      half8 v = *reinterpret_cast<const half8*>(src + k * 8);
#pragma unroll
      for (int e = 0; e < 8; ++e)
        lds[(fo + k * 8 + e) * 132 + w] = (float)v[e];
    }
  }
  __syncthreads();
  {
    const int f_loc = t >> 2;
    const int w0    = (t & 3) * 32;
    float* dst = out + (size_t)b * (COUT_ * HW_) + (size_t)(ft * 64 + f_loc) * 128 + w0;
#pragma unroll
    for (int k = 0; k < 8; ++k) {
      f4 v4;
#pragma unroll
      for (int e = 0; e < 4; ++e) v4[e] = lds[f_loc * 132 + w0 + k * 4 + e];
      *reinterpret_cast<f4*>(dst + k * 4) = v4;
    }
  }
}

extern "C" void kernel_launch(void* const* d_in, const int* in_sizes, int n_in,
                              void* d_out, int out_size, void* d_ws, size_t ws_size,
                              hipStream_t stream) {
  const float* flow   = (const float*)d_in[0];
  const float* de_out = (const float*)d_in[1];
  const float* Wq = (const float*)d_in[2];
  const float* bq = (const float*)d_in[3];
  const float* Wk = (const float*)d_in[4];
  const float* bk = (const float*)d_in[5];
  const float* Wv = (const float*)d_in[6];
  const float* bv = (const float*)d_in[7];
  float* out = (float*)d_out;

  u16* Qws = (u16*)d_ws;                 // [b][w][h][d]            fp16
  u16* Kws = Qws + Q_ELEMS;              // [b][w][h][d]            fp16
  u16* Vws = Kws + Q_ELEMS;              // [b][w][g>>3][c][g&7]    fp16
  u16* W16 = Vws + V_ELEMS;              // [Wk16|Wq16|Wv16]        fp16
  u16* Tws = W16 + W16_ELEMS;            // [b][w][c][h]            fp16

  wconv_kernel<<<96, 256, 0, stream>>>(Wk, Wq, Wv, W16);
  qkv_kernel<<<2 * B_ * H_ * 2, 256, 0, stream>>>(flow, de_out, W16, bq, bk, bv,
                                                  Qws, Kws, Vws);
  if (ws_size >= (size_t)WS_NEED) {
    attn_kernel<1><<<B_ * W_, 256, 0, stream>>>(Qws, Kws, Vws, Tws, out);
    transpose_kernel<<<B_ * 512, 256, 0, stream>>>(Tws, out);
  } else {
    attn_kernel<0><<<B_ * W_, 256, 0, stream>>>(Qws, Kws, Vws, Tws, out);
  }
}